// Round 3
// baseline (129.151 us; speedup 1.0000x reference)
//
#include <hip/hip_runtime.h>
#include <math.h>

#define N_ROWS 256
#define NB 8732
#define NB4 2183              // NB / 4 (exact)
#define CHUNKS 9              // 8 full blocks of 256 groups + 1 partial (135)
#define TOTAL_BLOCKS (N_ROWS * CHUNKS)
#define CNT_OFFSET_BYTES (TOTAL_BLOCKS * 16)   // partials: TOTAL_BLOCKS x float4

typedef float f4 __attribute__((ext_vector_type(4)));
typedef int   i4 __attribute__((ext_vector_type(4)));

__device__ __forceinline__ float smooth_l1(float d) {
    float ad = fabsf(d);
    return ad < 1.0f ? 0.5f * d * d : ad - 0.5f;
}

// BCE with logits, y = 0 (used by fallback top-K path only; accurate version)
__device__ __forceinline__ float bce_y0(float x) {
    return fmaxf(x, 0.0f) + log1pf(expf(-fabsf(x)));
}

__global__ __launch_bounds__(256) void fused_kernel(
    const float* __restrict__ ploc, const float* __restrict__ plabel,
    const float* __restrict__ gloc, const int* __restrict__ glabel,
    const float* __restrict__ dboxes, float* __restrict__ ws,
    unsigned* __restrict__ cnt, float* __restrict__ out) {
    const int row = blockIdx.x;
    const int chunk = blockIdx.y;
    const int tid = threadIdx.x;
    const int g = chunk * 256 + tid;

    float sl1acc = 0.0f, conAll = 0.0f, conPos = 0.0f, posCnt = 0.0f;

    if (g < NB4) {
        const f4* __restrict__ ploc4 = (const f4*)ploc;
        const f4* __restrict__ gloc4 = (const f4*)gloc;
        const f4* __restrict__ db4   = (const f4*)dboxes;
        const f4* __restrict__ pl4   = (const f4*)plabel;
        const i4* __restrict__ gl4   = (const i4*)glabel;

        const int rb = row * 4 * NB4;
        const int rs = row * NB4;

        f4 p0 = __builtin_nontemporal_load(&ploc4[rb + 0 * NB4 + g]);
        f4 p1 = __builtin_nontemporal_load(&ploc4[rb + 1 * NB4 + g]);
        f4 p2 = __builtin_nontemporal_load(&ploc4[rb + 2 * NB4 + g]);
        f4 p3 = __builtin_nontemporal_load(&ploc4[rb + 3 * NB4 + g]);
        f4 q0 = __builtin_nontemporal_load(&gloc4[rb + 0 * NB4 + g]);
        f4 q1 = __builtin_nontemporal_load(&gloc4[rb + 1 * NB4 + g]);
        f4 q2 = __builtin_nontemporal_load(&gloc4[rb + 2 * NB4 + g]);
        f4 q3 = __builtin_nontemporal_load(&gloc4[rb + 3 * NB4 + g]);
        f4 d0 = db4[0 * NB4 + g];   // dboxes reused across rows: keep cached
        f4 d1 = db4[1 * NB4 + g];
        f4 d2 = db4[2 * NB4 + g];
        f4 d3 = db4[3 * NB4 + g];
        i4 lb = __builtin_nontemporal_load(&gl4[rs + g]);
        f4 px = __builtin_nontemporal_load(&pl4[rs + g]);

#pragma unroll
        for (int k = 0; k < 4; ++k) {
            float rw2 = __builtin_amdgcn_rcpf(d2[k]);
            float rw3 = __builtin_amdgcn_rcpf(d3[k]);
            float gx = (q0[k] - d0[k]) * rw2;
            float gy = (q1[k] - d1[k]) * rw3;
            float gw = __logf(q2[k] * rw2);
            float gh = __logf(q3[k] * rw3);
            float s = smooth_l1(p0[k] - gx)
                    + smooth_l1(p1[k] - gy)
                    + smooth_l1(p2[k] - gw)
                    + smooth_l1(p3[k] - gh);
            int lab = lb[k];
            float x = px[k];
            float con = fmaxf(x, 0.0f) - x * (float)lab
                      + __logf(1.0f + __expf(-fabsf(x)));
            conAll += con;
            float m = (lab > 0) ? 1.0f : 0.0f;
            posCnt += m;
            sl1acc += m * s;
            conPos += m * con;
        }
    }

    // block reduction: wave64 shuffle, then LDS across 4 waves
    float v0 = sl1acc, v1 = conAll, v2 = conPos, v3 = posCnt;
#pragma unroll
    for (int off = 32; off > 0; off >>= 1) {
        v0 += __shfl_down(v0, off);
        v1 += __shfl_down(v1, off);
        v2 += __shfl_down(v2, off);
        v3 += __shfl_down(v3, off);
    }
    __shared__ float sm[4][4];
    __shared__ int isLast;
    const int wid = tid >> 6, lane = tid & 63;
    if (lane == 0) {
        sm[wid][0] = v0; sm[wid][1] = v1; sm[wid][2] = v2; sm[wid][3] = v3;
    }
    __syncthreads();
    if (tid == 0) {
        f4 part;
        part.x = sm[0][0] + sm[1][0] + sm[2][0] + sm[3][0];
        part.y = sm[0][1] + sm[1][1] + sm[2][1] + sm[3][1];
        part.z = sm[0][2] + sm[1][2] + sm[2][2] + sm[3][2];
        part.w = sm[0][3] + sm[1][3] + sm[2][3] + sm[3][3];
        // [chunk][row] layout -> coalesced reads in the final phase
        ((f4*)ws)[chunk * N_ROWS + row] = part;
        __threadfence();                       // release partials (device scope)
        unsigned old = atomicAdd(cnt, 1u);
        isLast = (old == TOTAL_BLOCKS - 1) ? 1 : 0;
    }
    __syncthreads();
    if (!isLast) return;

    // ---- final phase: executed by the single last-arriving block ----
    __threadfence();                           // acquire all partials
    {
        const int r = tid;                     // one thread per batch row
        float sl1 = 0.f, cAll = 0.f, cPos = 0.f, posf = 0.f;
#pragma unroll
        for (int c = 0; c < CHUNKS; ++c) {
            f4 p = ((const f4*)ws)[c * N_ROWS + r];
            sl1 += p.x; cAll += p.y; cPos += p.z; posf += p.w;
        }
        const int pos = (int)(posf + 0.5f);
        const long long K = 3LL * (long long)pos;

        float closs;
        if (pos == 0) {
            closs = 0.0f;
        } else if (K >= (long long)NB) {
            closs = cAll;                      // neg_mask selects everything
        } else {
            // General hard-negative-mining fallback (dead for this data):
            // top-K negative con values via radix search on uint bit pattern
            // (all con >= 0, so uint order == float order).
            const int Ki = (int)K;
            const float* plRow = plabel + r * NB;
            const int* glRow = glabel + r * NB;
            unsigned cur = 0;
            for (int bit = 31; bit >= 0; --bit) {
                unsigned trial = cur | (1u << bit);
                int c2 = 0;
                for (int j = 0; j < NB; ++j) {
                    if (glRow[j] > 0) continue;
                    float con = bce_y0(plRow[j]);
                    if (__float_as_uint(con) >= trial) c2++;
                }
                if (c2 >= Ki) cur = trial;
            }
            const float thr = __uint_as_float(cur);
            int cntG = 0; float sumG = 0.f;
            for (int j = 0; j < NB; ++j) {
                if (glRow[j] > 0) continue;
                float con = bce_y0(plRow[j]);
                if (con > thr) { cntG++; sumG += con; }
            }
            closs = cPos + sumG + (float)(Ki - cntG) * thr;
        }

        float loss = (pos > 0) ? (sl1 + closs) / (float)pos : 0.0f;

#pragma unroll
        for (int off = 32; off > 0; off >>= 1) loss += __shfl_down(loss, off);
        __shared__ float sm2[4];
        if (lane == 0) sm2[wid] = loss;
        __syncthreads();
        if (tid == 0) {
            out[0] = (sm2[0] + sm2[1] + sm2[2] + sm2[3]) * (1.0f / 256.0f);
        }
    }
}

extern "C" void kernel_launch(void* const* d_in, const int* in_sizes, int n_in,
                              void* d_out, int out_size, void* d_ws, size_t ws_size,
                              hipStream_t stream) {
    const float* ploc   = (const float*)d_in[0];
    const float* plabel = (const float*)d_in[1];
    const float* gloc   = (const float*)d_in[2];
    const int*   glabel = (const int*)d_in[3];
    const float* dboxes = (const float*)d_in[4];
    float* ws  = (float*)d_ws;
    unsigned* cnt = (unsigned*)((char*)d_ws + CNT_OFFSET_BYTES);
    float* out = (float*)d_out;

    // zero the arrival counter every call (graph-capture-safe memset node)
    hipMemsetAsync(cnt, 0, sizeof(unsigned), stream);

    dim3 grid(N_ROWS, CHUNKS);
    hipLaunchKernelGGL(fused_kernel, grid, dim3(256), 0, stream,
                       ploc, plabel, gloc, glabel, dboxes, ws, cnt, out);
}

// Round 4
// 22.525 us; speedup vs baseline: 5.7337x; 5.7337x over previous
//
#include <hip/hip_runtime.h>
#include <math.h>

#define N_ROWS 256
#define NB 8732
#define NB4 2183              // NB / 4 (exact)
#define CHUNKS 9              // 8 full blocks of 256 float4-groups + 1 partial (135)

typedef float f4 __attribute__((ext_vector_type(4)));
typedef int   i4 __attribute__((ext_vector_type(4)));

__device__ __forceinline__ float smooth_l1(float d) {
    float ad = fabsf(d);
    return ad < 1.0f ? 0.5f * d * d : ad - 0.5f;
}

// BCE with logits, y = 0 (used by fallback top-K path only; accurate version)
__device__ __forceinline__ float bce_y0(float x) {
    return fmaxf(x, 0.0f) + log1pf(expf(-fabsf(x)));
}

// one float4-group of anchors per thread; partials -> ws[chunk][row] (f4)
__global__ __launch_bounds__(256) void partial_kernel(
    const float* __restrict__ ploc, const float* __restrict__ plabel,
    const float* __restrict__ gloc, const int* __restrict__ glabel,
    const float* __restrict__ dboxes, float* __restrict__ ws) {
    const int row = blockIdx.x;
    const int chunk = blockIdx.y;
    const int tid = threadIdx.x;
    const int g = chunk * 256 + tid;

    float sl1acc = 0.0f, conAll = 0.0f, conPos = 0.0f, posCnt = 0.0f;

    if (g < NB4) {
        const f4* __restrict__ ploc4 = (const f4*)ploc;
        const f4* __restrict__ gloc4 = (const f4*)gloc;
        const f4* __restrict__ db4   = (const f4*)dboxes;
        const f4* __restrict__ pl4   = (const f4*)plabel;
        const i4* __restrict__ gl4   = (const i4*)glabel;

        const int rb = row * 4 * NB4;
        const int rs = row * NB4;

        f4 p0 = ploc4[rb + 0 * NB4 + g];
        f4 p1 = ploc4[rb + 1 * NB4 + g];
        f4 p2 = ploc4[rb + 2 * NB4 + g];
        f4 p3 = ploc4[rb + 3 * NB4 + g];
        f4 q0 = gloc4[rb + 0 * NB4 + g];
        f4 q1 = gloc4[rb + 1 * NB4 + g];
        f4 q2 = gloc4[rb + 2 * NB4 + g];
        f4 q3 = gloc4[rb + 3 * NB4 + g];
        f4 d0 = db4[0 * NB4 + g];
        f4 d1 = db4[1 * NB4 + g];
        f4 d2 = db4[2 * NB4 + g];
        f4 d3 = db4[3 * NB4 + g];
        i4 lb = gl4[rs + g];
        f4 px = pl4[rs + g];

#pragma unroll
        for (int k = 0; k < 4; ++k) {
            float rw2 = __builtin_amdgcn_rcpf(d2[k]);
            float rw3 = __builtin_amdgcn_rcpf(d3[k]);
            float gx = (q0[k] - d0[k]) * rw2;
            float gy = (q1[k] - d1[k]) * rw3;
            float gw = __logf(q2[k] * rw2);
            float gh = __logf(q3[k] * rw3);
            float s = smooth_l1(p0[k] - gx)
                    + smooth_l1(p1[k] - gy)
                    + smooth_l1(p2[k] - gw)
                    + smooth_l1(p3[k] - gh);
            int lab = lb[k];
            float x = px[k];
            float con = fmaxf(x, 0.0f) - x * (float)lab
                      + __logf(1.0f + __expf(-fabsf(x)));
            conAll += con;
            float m = (lab > 0) ? 1.0f : 0.0f;
            posCnt += m;
            sl1acc += m * s;
            conPos += m * con;
        }
    }

    // block reduction: wave64 shuffle, then LDS across 4 waves
    float v0 = sl1acc, v1 = conAll, v2 = conPos, v3 = posCnt;
#pragma unroll
    for (int off = 32; off > 0; off >>= 1) {
        v0 += __shfl_down(v0, off);
        v1 += __shfl_down(v1, off);
        v2 += __shfl_down(v2, off);
        v3 += __shfl_down(v3, off);
    }
    __shared__ float sm[4][4];
    const int wid = tid >> 6, lane = tid & 63;
    if (lane == 0) {
        sm[wid][0] = v0; sm[wid][1] = v1; sm[wid][2] = v2; sm[wid][3] = v3;
    }
    __syncthreads();
    if (tid == 0) {
        f4 part;
        part.x = sm[0][0] + sm[1][0] + sm[2][0] + sm[3][0];
        part.y = sm[0][1] + sm[1][1] + sm[2][1] + sm[3][1];
        part.z = sm[0][2] + sm[1][2] + sm[2][2] + sm[3][2];
        part.w = sm[0][3] + sm[1][3] + sm[2][3] + sm[3][3];
        ((f4*)ws)[chunk * N_ROWS + row] = part;   // [chunk][row]: coalesced later
    }
}

__global__ __launch_bounds__(256) void final_kernel(
    const float* __restrict__ ws, const float* __restrict__ plabel,
    const int* __restrict__ glabel, float* __restrict__ out) {
    const int r = threadIdx.x;  // one thread per batch row
    float sl1 = 0.f, cAll = 0.f, cPos = 0.f, posf = 0.f;
#pragma unroll
    for (int c = 0; c < CHUNKS; ++c) {
        f4 p = ((const f4*)ws)[c * N_ROWS + r];
        sl1 += p.x; cAll += p.y; cPos += p.z; posf += p.w;
    }
    const int pos = (int)(posf + 0.5f);
    const long long K = 3LL * (long long)pos;

    float closs;
    if (pos == 0) {
        closs = 0.0f;
    } else if (K >= (long long)NB) {
        closs = cAll;                      // neg_mask selects everything
    } else {
        // General hard-negative-mining fallback (dead for this data):
        // top-K negative con values via radix search on the uint bit
        // pattern (all con >= 0, so uint order == float order).
        const int Ki = (int)K;
        const float* plRow = plabel + r * NB;
        const int* glRow = glabel + r * NB;
        unsigned cur = 0;
        for (int bit = 31; bit >= 0; --bit) {
            unsigned trial = cur | (1u << bit);
            int c2 = 0;
            for (int j = 0; j < NB; ++j) {
                if (glRow[j] > 0) continue;
                float con = bce_y0(plRow[j]);
                if (__float_as_uint(con) >= trial) c2++;
            }
            if (c2 >= Ki) cur = trial;
        }
        const float thr = __uint_as_float(cur);
        int cntG = 0; float sumG = 0.f;
        for (int j = 0; j < NB; ++j) {
            if (glRow[j] > 0) continue;
            float con = bce_y0(plRow[j]);
            if (con > thr) { cntG++; sumG += con; }
        }
        closs = cPos + sumG + (float)(Ki - cntG) * thr;
    }

    float loss = (pos > 0) ? (sl1 + closs) / (float)pos : 0.0f;

    // mean over 256 rows
#pragma unroll
    for (int off = 32; off > 0; off >>= 1) loss += __shfl_down(loss, off);
    __shared__ float sm[4];
    const int wid = threadIdx.x >> 6, lane = threadIdx.x & 63;
    if (lane == 0) sm[wid] = loss;
    __syncthreads();
    if (threadIdx.x == 0) {
        out[0] = (sm[0] + sm[1] + sm[2] + sm[3]) * (1.0f / 256.0f);
    }
}

extern "C" void kernel_launch(void* const* d_in, const int* in_sizes, int n_in,
                              void* d_out, int out_size, void* d_ws, size_t ws_size,
                              hipStream_t stream) {
    const float* ploc   = (const float*)d_in[0];
    const float* plabel = (const float*)d_in[1];
    const float* gloc   = (const float*)d_in[2];
    const int*   glabel = (const int*)d_in[3];
    const float* dboxes = (const float*)d_in[4];
    float* ws  = (float*)d_ws;
    float* out = (float*)d_out;

    dim3 grid(N_ROWS, CHUNKS);
    hipLaunchKernelGGL(partial_kernel, grid, dim3(256), 0, stream,
                       ploc, plabel, gloc, glabel, dboxes, ws);
    hipLaunchKernelGGL(final_kernel, dim3(1), dim3(256), 0, stream,
                       ws, plabel, glabel, out);
}